// Round 1
// baseline (2198.787 us; speedup 1.0000x reference)
//
#include <hip/hip_runtime.h>

// RecurrentEncoder: proj(16->512)+relu, 3-layer LSTM (H=512), out head (512->16).
// B=256, T=128. 384 sequential (t,layer) stages, each [256,1024]@[1024,2048] bf16
// MFMA GEMM + fp32 LSTM cell. One kernel launch per stage (round-0 baseline).

typedef __attribute__((ext_vector_type(8))) short bf16x8;     // 8 bf16 = 4 VGPRs (MFMA A/B frag)
typedef __attribute__((ext_vector_type(4))) float f32x4;      // MFMA C/D frag
typedef __attribute__((ext_vector_type(8))) unsigned short us8;

#define B_  256
#define T_  128
#define FIN 16
#define H_  512
#define G4  2048   // 4*H gate width
#define KK  1024   // 2*H contraction

static __device__ __forceinline__ float bf2f(unsigned short u){
  return __uint_as_float(((unsigned)u) << 16);
}
static __device__ __forceinline__ unsigned short f2bf(float f){  // RNE
  unsigned u = __float_as_uint(f);
  u += 0x7fffu + ((u >> 16) & 1u);
  return (unsigned short)(u >> 16);
}
static __device__ __forceinline__ float sigm(float x){ return 1.f/(1.f + __expf(-x)); }
static __device__ __forceinline__ float tanh_(float x){ return 1.f - 2.f/(__expf(2.f*x) + 1.f); }

// ---- prep: lstm_w fp32 [3][1024][2048] -> bf16 in MFMA-B-fragment order ----
// dst layout: [l][J=128][s=32][lane=64][e=8]; gate interleave j' = hcol*4 + gate.
// For 16x16x32 bf16 MFMA, B frag: col = lane&15, k = 8*(lane>>4)+e.
__global__ __launch_bounds__(256) void k_wconv(const float* __restrict__ w,
                                               unsigned short* __restrict__ wf){
  long d8 = ((long)blockIdx.x*256 + threadIdx.x) * 8;   // 786432 threads * 8 elems
  int lane = (int)((d8 >> 3) & 63);
  int s    = (int)((d8 >> 9) & 31);
  int J    = (int)((d8 >> 14) & 127);
  int l    = (int)(d8 >> 21);
  int jj = lane & 15, khi = lane >> 4;
  int jp = J*16 + jj;
  int co = (jp & 3)*512 + (jp >> 2);        // original col = gate*512 + hcol
  int kbase = s*32 + khi*8;
  us8 o;
  #pragma unroll
  for (int e = 0; e < 8; ++e)
    o[e] = f2bf(w[((long)(l*1024 + kbase + e))*2048 + co]);
  *(us8*)(wf + d8) = o;
}

// ---- luxury prep: xp = relu(x @ pw + pb) -> bf16 [B*T][512] ----
__global__ __launch_bounds__(256) void k_xp(const float* __restrict__ x,
                                            const float* __restrict__ pw,
                                            const float* __restrict__ pb,
                                            unsigned short* __restrict__ xpall){
  __shared__ float sw[FIN*H_];
  __shared__ float sb[H_];
  int tid = threadIdx.x;
  for (int i = tid; i < FIN*H_; i += 256) sw[i] = pw[i];
  for (int i = tid; i < H_;     i += 256) sb[i] = pb[i];
  __syncthreads();
  int r0 = blockIdx.x * 64;
  int c0 = tid * 2;
  for (int rr = 0; rr < 64; ++rr){
    int r = r0 + rr;
    const float* xr = x + (long)r*FIN;
    float a0 = sb[c0], a1 = sb[c0+1];
    #pragma unroll
    for (int f = 0; f < FIN; ++f){
      float xv = xr[f];
      a0 += xv * sw[f*H_ + c0];
      a1 += xv * sw[f*H_ + c0 + 1];
    }
    ushort2 tmp;
    tmp.x = f2bf(fmaxf(a0, 0.f));
    tmp.y = f2bf(fmaxf(a1, 0.f));
    *(ushort2*)(xpall + (long)r*H_ + c0) = tmp;
  }
}

// ---- compact path: init d_out with out_b (atomics add partials on top) ----
__global__ void k_iout(float* __restrict__ dout, const float* __restrict__ ob){
  int i = blockIdx.x*256 + threadIdx.x;
  if (i < B_*T_*16) dout[i] = ob[i & 15];
}

// ---- luxury epilogue: y = h2all @ out_w + out_b ----
__global__ __launch_bounds__(256) void k_out(const unsigned short* __restrict__ h2,
                                             const float* __restrict__ ow,
                                             const float* __restrict__ ob,
                                             float* __restrict__ dout){
  __shared__ float sw[H_*16];
  int tid = threadIdx.x;
  for (int i = tid; i < H_*16; i += 256) sw[i] = ow[i];
  __syncthreads();
  int r0 = blockIdx.x * 128;
  #pragma unroll
  for (int q = 0; q < 8; ++q){
    int oid = tid + 256*q;            // 2048 outputs per block
    int rr = oid >> 4, o = oid & 15;
    int r = r0 + rr;
    const us8* hp = (const us8*)(h2 + (long)r*H_);
    float acc = ob[o];
    for (int k8 = 0; k8 < H_/8; ++k8){
      us8 v = hp[k8];
      #pragma unroll
      for (int e = 0; e < 8; ++e) acc += bf2f(v[e]) * sw[(k8*8 + e)*16 + o];
    }
    dout[(long)r*16 + o] = acc;
  }
}

// ---- one (t, layer) stage ----
// grid 512: m = bid>>6 (8 batch tiles of 32), n = XCD-clustered gate-slice (64 slices
// of 32 j' = 8 hcols). n clustered per XCD so each XCD's W slice (1.5 MB, 3 layers)
// stays L2-resident across all 384 stages; fresh activations stream via L3.
__global__ __launch_bounds__(256, 2) void k_stage(
    const float* __restrict__ x, const float* __restrict__ pw, const float* __restrict__ pb,
    const unsigned short* __restrict__ wf, const float* __restrict__ lb,
    const float* __restrict__ ow, float* __restrict__ dout,
    float* __restrict__ cbuf, unsigned short* __restrict__ hb,
    const unsigned short* __restrict__ xpall, unsigned short* __restrict__ h2all,
    int t, int l, int lux)
{
  __shared__ unsigned char Ab[32*2048];   // [32 rows][1024 k] bf16, XOR-swizzled
  __shared__ float gsm[32*36];            // gates, padded row stride 36 floats
  __shared__ float xrow[32*16];           // compact-path x staging
  __shared__ float hcell[32*8];           // compact-path h2 staging

  const int tid = threadIdx.x;
  const int bid = blockIdx.x;
  const int m = bid >> 6;                          // batch tile 0..7
  const int n = ((bid & 7) << 3) | ((bid >> 3) & 7); // gate slice 0..63, XCD-clustered
  const int pwr = t & 1, prd = pwr ^ 1;            // h double-buffer parity
  const int bg0 = m * 32;

  // ---- fill A tile: cols [0,512) = layer input, cols [512,1024) = own h_prev ----
  { // right half: h[l] @ t-1, no relu
    const unsigned short* src = hb + (((long)prd*3 + l)*256 + bg0)*512;
    for (int i = 0; i < 8; ++i){
      int cid = tid + 256*i;                 // 2048 chunks of 16B
      int row = cid >> 6, cc = cid & 63;
      us8 v = *(const us8*)(src + (long)row*512 + cc*8);
      *(us8*)(Ab + ((row*2048 + 1024 + cc*16) ^ ((row & 7) << 4))) = v;
    }
  }
  if (l > 0){ // left half: relu(h[l-1] @ t)
    const unsigned short* src = hb + (((long)pwr*3 + (l-1))*256 + bg0)*512;
    for (int i = 0; i < 8; ++i){
      int cid = tid + 256*i;
      int row = cid >> 6, cc = cid & 63;
      us8 v = *(const us8*)(src + (long)row*512 + cc*8);
      #pragma unroll
      for (int e = 0; e < 8; ++e) v[e] = (v[e] & 0x8000u) ? (unsigned short)0 : v[e];
      *(us8*)(Ab + ((row*2048 + cc*16) ^ ((row & 7) << 4))) = v;
    }
  } else if (lux){ // left half: precomputed xp (already relu'd)
    const unsigned short* src = xpall + ((long)bg0*T_ + t)*512;
    for (int i = 0; i < 8; ++i){
      int cid = tid + 256*i;
      int row = cid >> 6, cc = cid & 63;
      us8 v = *(const us8*)(src + (long)row*(T_*512) + cc*8);
      *(us8*)(Ab + ((row*2048 + cc*16) ^ ((row & 7) << 4))) = v;
    }
  } else { // compute xp on the fly
    {
      int e2 = tid*2;
      int br = e2 >> 4, f = e2 & 15;
      const float* xr = x + ((long)(bg0 + br)*T_ + t)*FIN;
      xrow[e2] = xr[f]; xrow[e2+1] = xr[f+1];
    }
    __syncthreads();
    for (int i = 0; i < 8; ++i){
      int cid = tid + 256*i;
      int row = cid >> 6, cc = cid & 63;
      int c0 = cc*8;
      us8 vv;
      #pragma unroll
      for (int j = 0; j < 8; ++j){
        float a = pb[c0 + j];
        #pragma unroll
        for (int f = 0; f < FIN; ++f) a += xrow[row*16 + f] * pw[f*H_ + c0 + j];
        vv[j] = f2bf(fmaxf(a, 0.f));
      }
      *(us8*)(Ab + ((row*2048 + cc*16) ^ ((row & 7) << 4))) = vv;
    }
  }
  __syncthreads();

  // ---- GEMM: gates[32 x 32] = A[32 x 1024] @ W[1024 x 32] ----
  const int lane = tid & 63, wid = tid >> 6;
  const int wm = wid >> 1, wn = wid & 1;           // wave: 16 rows x 16 cols
  const int J = n*2 + wn;
  const int arow = wm*16 + (lane & 15);
  const unsigned abase = (unsigned)arow*2048 + ((lane >> 4) << 4);
  const unsigned axor = (unsigned)((arow & 7) << 4);
  const unsigned short* bp = wf + ((((long)l*128 + J)*32)*64 + lane)*8;

  f32x4 acc = {0.f, 0.f, 0.f, 0.f};
  #pragma unroll
  for (int s = 0; s < 32; ++s){
    bf16x8 af = *(const bf16x8*)(Ab + ((abase + s*64) ^ axor));
    bf16x8 bfr = *(const bf16x8*)(bp + (long)s*512);
    acc = __builtin_amdgcn_mfma_f32_16x16x32_bf16(af, bfr, acc, 0, 0, 0);
  }
  { // D frag: col = lane&15, row = (lane>>4)*4 + r
    int colb = wn*16 + (lane & 15);
    int rowb = wm*16 + ((lane >> 4) << 2);
    #pragma unroll
    for (int r = 0; r < 4; ++r) gsm[(rowb + r)*36 + colb] = acc[r];
  }
  __syncthreads();

  // ---- LSTM cell: one (batch row, hcol) per thread; j' = hcol*4 + {i,g,f,o} ----
  {
    int bl = tid >> 3, hc = tid & 7;
    float4 g4 = *(float4*)(&gsm[bl*36 + hc*4]);
    int hcol = n*8 + hc;
    int bgl = bg0 + bl;
    float iv = g4.x + lb[l*G4 + hcol];
    float gv = g4.y + lb[l*G4 + 512 + hcol];
    float fv = g4.z + lb[l*G4 + 1024 + hcol];
    float ov = g4.w + lb[l*G4 + 1536 + hcol];
    long coff = ((long)l*256 + bgl)*512 + hcol;
    float cp = cbuf[coff];
    float cn = sigm(fv + 1.f)*cp + sigm(iv)*tanh_(gv);
    float hn = sigm(ov)*tanh_(cn);
    cbuf[coff] = cn;
    hb[(((long)pwr*3 + l)*256 + bgl)*512 + hcol] = f2bf(hn);
    if (l == 2){
      if (lux) h2all[((long)bgl*T_ + t)*512 + hcol] = f2bf(hn);
      else     hcell[bl*8 + hc] = hn;
    }
  }
  if (l == 2 && !lux){ // fused output head, partial over this WG's 8 hcols
    __syncthreads();
    #pragma unroll
    for (int q = 0; q < 2; ++q){
      int oid = tid + 256*q;
      int bl = oid >> 4, o = oid & 15;
      float a = 0.f;
      #pragma unroll
      for (int hc = 0; hc < 8; ++hc) a += hcell[bl*8 + hc] * ow[(n*8 + hc)*16 + o];
      atomicAdd(dout + ((long)(bg0 + bl)*T_ + t)*16 + o, a);
    }
  }
}

extern "C" void kernel_launch(void* const* d_in, const int* in_sizes, int n_in,
                              void* d_out, int out_size, void* d_ws, size_t ws_size,
                              hipStream_t stream)
{
  const float* x  = (const float*)d_in[0];
  const float* pw = (const float*)d_in[1];
  const float* pb = (const float*)d_in[2];
  const float* lw = (const float*)d_in[3];
  const float* lb = (const float*)d_in[4];
  const float* ow = (const float*)d_in[5];
  const float* ob = (const float*)d_in[6];
  float* dout = (float*)d_out;

  char* ws = (char*)d_ws;
  size_t off = 0;
  auto carve = [&](size_t bytes){ char* p = ws + off; off += (bytes + 255) & ~(size_t)255; return p; };
  unsigned short* wf    = (unsigned short*)carve(3ull*1024*2048*2);   // 12.6 MB
  float*          cbuf  = (float*)carve(3ull*256*512*4);              // 1.5 MB
  unsigned short* hbuf  = (unsigned short*)carve(2ull*3*256*512*2);   // 1.5 MB
  unsigned short* xpall = (unsigned short*)carve((size_t)B_*T_*H_*2); // 33.5 MB (luxury)
  unsigned short* h2all = (unsigned short*)carve((size_t)B_*T_*H_*2); // 33.5 MB (luxury)
  int lux = (ws_size >= off) ? 1 : 0;

  // zero c state + both h parities (cbuf/hbuf are adjacent, 256B-aligned sizes)
  hipMemsetAsync(cbuf, 0, 3ull*256*512*4 + 2ull*3*256*512*2, stream);

  k_wconv<<<3072, 256, 0, stream>>>(lw, wf);
  if (lux) k_xp<<<512, 256, 0, stream>>>(x, pw, pb, xpall);
  else     k_iout<<<2048, 256, 0, stream>>>(dout, ob);

  for (int t = 0; t < T_; ++t)
    for (int l = 0; l < 3; ++l)
      k_stage<<<512, 256, 0, stream>>>(x, pw, pb, wf, lb, ow, dout,
                                       cbuf, hbuf, xpall, h2all, t, l, lux);

  if (lux) k_out<<<256, 256, 0, stream>>>(h2all, ow, ob, dout);
}